// Round 1
// baseline (545.024 us; speedup 1.0000x reference)
//
#include <hip/hip_runtime.h>
#include <hip/hip_bf16.h>

#define CDIV(a,b) (((a)+(b)-1)/(b))

// ---------------- CSR build ----------------

__global__ void k_deg(const int* __restrict__ dst, int E, int* __restrict__ deg){
  int i = blockIdx.x*256 + threadIdx.x;
  if (i < E) atomicAdd(&deg[dst[i]], 1);
}

__global__ void k_scanA(const int* __restrict__ deg, int n, int* __restrict__ incl, int* __restrict__ part){
  __shared__ int s[256];
  int t = threadIdx.x, i = blockIdx.x*256 + t;
  int v = (i<n) ? deg[i] : 0;
  s[t] = v; __syncthreads();
  for (int d=1; d<256; d<<=1){
    int u = (t>=d) ? s[t-d] : 0;
    __syncthreads();
    s[t] += u;
    __syncthreads();
  }
  if (i<n) incl[i] = s[t];
  if (t==255) part[blockIdx.x] = s[255];
}

__global__ void k_scanB(int* __restrict__ part, int nb){
  __shared__ int s[256];
  int t = threadIdx.x;
  int v = (t<nb) ? part[t] : 0;
  s[t] = v; __syncthreads();
  for (int d=1; d<256; d<<=1){
    int u = (t>=d) ? s[t-d] : 0;
    __syncthreads();
    s[t] += u;
    __syncthreads();
  }
  if (t<nb) part[t] = s[t] - v;  // exclusive
}

__global__ void k_scanC(const int* __restrict__ incl, const int* __restrict__ part, int n, int* __restrict__ off){
  int i = blockIdx.x*256 + threadIdx.x;
  if (i<n) off[i+1] = incl[i] + part[blockIdx.x];
  if (i==0) off[0] = 0;
}

__global__ void k_fill(const int* __restrict__ src, const int* __restrict__ dst, int E,
                       const int* __restrict__ off, int* __restrict__ fill, int* __restrict__ csr){
  int e = blockIdx.x*256 + threadIdx.x;
  if (e < E){
    int d = dst[e];
    int p = atomicAdd(&fill[d], 1);
    csr[off[d] + p] = src[e];
  }
}

// ---------------- weight panel: Wt[258][dout]: rows 0..127 = Wl^T, 128..255 = Wr^T,
// row 256 = BN scale, row 257 = BN shift (absorbs bl) ----------------

__global__ void k_wt(const float* __restrict__ Wl, const float* __restrict__ bl, const float* __restrict__ Wr,
                     const float* __restrict__ g, const float* __restrict__ b,
                     const float* __restrict__ rm, const float* __restrict__ rv,
                     int dout, float* __restrict__ Wt){
  int idx = blockIdx.x*256 + threadIdx.x;
  if (idx >= 258*dout) return;
  int k = idx / dout, j = idx - k*dout;
  float v;
  if (k < 128) v = Wl[j*128 + k];
  else if (k < 256) v = Wr[j*128 + (k-128)];
  else {
    float sc = g[j] * rsqrtf(rv[j] + 1e-5f);
    v = (k == 256) ? sc : ((bl[j] - rm[j])*sc + b[j]);
  }
  Wt[idx] = v;
}

// ---------------- mean aggregation: one wave per node, CSR gather ----------------

__global__ void k_agg(const float* __restrict__ hin, const int* __restrict__ off,
                      const int* __restrict__ csr, int n, float* __restrict__ mean){
  int w = (blockIdx.x*256 + threadIdx.x) >> 6;
  int lane = threadIdx.x & 63;
  if (w >= n) return;
  int s0 = off[w], s1 = off[w+1];
  const float2* hp = (const float2*)hin;
  float ax = 0.f, ay = 0.f;
  int e = s0;
  for (; e + 4 <= s1; e += 4){
    int i0 = csr[e], i1 = csr[e+1], i2 = csr[e+2], i3 = csr[e+3];
    float2 v0 = hp[(size_t)i0*64 + lane];
    float2 v1 = hp[(size_t)i1*64 + lane];
    float2 v2 = hp[(size_t)i2*64 + lane];
    float2 v3 = hp[(size_t)i3*64 + lane];
    ax += (v0.x + v1.x) + (v2.x + v3.x);
    ay += (v0.y + v1.y) + (v2.y + v3.y);
  }
  for (; e < s1; e++){
    int s = csr[e];
    float2 v = hp[(size_t)s*64 + lane];
    ax += v.x; ay += v.y;
  }
  int d = s1 - s0;
  float inv = 1.0f / (float)(d > 0 ? d : 1);
  float2 m; m.x = ax*inv; m.y = ay*inv;
  ((float2*)mean)[(size_t)w*64 + lane] = m;
}

// ---------------- fused dual-GEMM + BN (+ReLU): C[N][DOUT] = [mean|x] @ Wt, then scale/shift ----------------

template<int DOUT, bool RELU>
__global__ __launch_bounds__(256) void k_gemm(const float* __restrict__ mean, const float* __restrict__ xin,
                                              const float* __restrict__ Wt, float* __restrict__ out, int n){
  constexpr int TN = DOUT/32;   // 4 for dout=128, 2 for dout=64
  constexpr int KB = 64;
  __shared__ float A_s[64][KB+8];
  __shared__ float W_s[KB*DOUT];
  int t = threadIdx.x;
  int tx = t & 31, ty = t >> 5;
  int m0 = blockIdx.x * 64;
  float acc[8][TN];
  #pragma unroll
  for (int i=0;i<8;i++)
    #pragma unroll
    for (int nn=0;nn<TN;nn++) acc[i][nn] = 0.f;

  for (int kb=0; kb<4; kb++){
    int k0 = kb*KB;
    const float* srcA = (kb < 2) ? mean : xin;
    int ka = (kb < 2) ? k0 : (k0 - 128);
    int mr = t >> 4, kq = t & 15;
    #pragma unroll
    for (int r=0;r<4;r++){
      int m = mr + r*16;
      int row = m0 + m;
      float4 v = make_float4(0.f,0.f,0.f,0.f);
      if (row < n) v = *(const float4*)(srcA + (size_t)row*128 + ka + kq*4);
      *(float4*)&A_s[m][kq*4] = v;
    }
    {
      constexpr int F4 = KB*DOUT/4;
      const float4* wsrc = (const float4*)(Wt + (size_t)k0*DOUT);
      float4* wdst = (float4*)W_s;
      #pragma unroll
      for (int f=0; f<F4/256; f++) wdst[f*256 + t] = wsrc[f*256 + t];
    }
    __syncthreads();
    #pragma unroll 8
    for (int kk=0; kk<KB; kk++){
      float a[8];
      #pragma unroll
      for (int i=0;i<8;i++) a[i] = A_s[ty*8+i][kk];
      float w[TN];
      #pragma unroll
      for (int nn=0;nn<TN;nn++) w[nn] = W_s[kk*DOUT + tx*TN + nn];
      #pragma unroll
      for (int i=0;i<8;i++)
        #pragma unroll
        for (int nn=0;nn<TN;nn++)
          acc[i][nn] = fmaf(a[i], w[nn], acc[i][nn]);
    }
    __syncthreads();
  }

  float scale[TN], shift[TN];
  #pragma unroll
  for (int nn=0;nn<TN;nn++){
    scale[nn] = Wt[(size_t)256*DOUT + tx*TN + nn];
    shift[nn] = Wt[(size_t)257*DOUT + tx*TN + nn];
  }
  #pragma unroll
  for (int i=0;i<8;i++){
    int row = m0 + ty*8 + i;
    if (row >= n) break;
    float v[TN];
    #pragma unroll
    for (int nn=0;nn<TN;nn++){
      v[nn] = acc[i][nn]*scale[nn] + shift[nn];
      if (RELU) v[nn] = fmaxf(v[nn], 0.f);
    }
    if constexpr (TN == 4){
      *(float4*)(out + (size_t)row*DOUT + tx*4) = make_float4(v[0],v[1],v[2],v[3]);
    } else {
      *(float2*)(out + (size_t)row*DOUT + tx*2) = make_float2(v[0],v[1]);
    }
  }
}

// ---------------- final row L2-normalize (dout=64): one wave per row ----------------

__global__ void k_norm(float* __restrict__ out, int n){
  int w = (blockIdx.x*256 + threadIdx.x) >> 6;
  int lane = threadIdx.x & 63;
  if (w >= n) return;
  float v = out[(size_t)w*64 + lane];
  float ss = v*v;
  #pragma unroll
  for (int d=32; d>=1; d>>=1) ss += __shfl_xor(ss, d, 64);
  float s = 1.0f / fmaxf(sqrtf(ss), 1e-12f);
  out[(size_t)w*64 + lane] = v*s;
}

// ---------------- launcher ----------------

extern "C" void kernel_launch(void* const* d_in, const int* in_sizes, int n_in,
                              void* d_out, int out_size, void* d_ws, size_t ws_size,
                              hipStream_t stream){
  const float* x = (const float*)d_in[0];
  const int* ei  = (const int*)d_in[1];
  int N = in_sizes[0] / 128;
  int E = in_sizes[1] / 2;
  const int* esrc = ei;
  const int* edst = ei + E;

  const float *Wl[3], *bl[3], *Wr[3], *g[3], *bb[3], *rm[3], *rv[3];
  int dout[3];
  for (int i=0;i<3;i++){
    int base = 2 + 7*i;
    Wl[i]=(const float*)d_in[base];   bl[i]=(const float*)d_in[base+1];
    Wr[i]=(const float*)d_in[base+2]; g[i] =(const float*)d_in[base+3];
    bb[i]=(const float*)d_in[base+4]; rm[i]=(const float*)d_in[base+5];
    rv[i]=(const float*)d_in[base+6];
    dout[i] = in_sizes[base] / 128;
  }

  char* p = (char*)d_ws;
  size_t o = 0;
  auto alloc = [&](size_t bytes)->void*{ void* r = p + o; o += (bytes + 255) & ~(size_t)255; return r; };
  int* deg   = (int*)alloc((size_t)N*4);
  int* off   = (int*)alloc((size_t)(N+1)*4);
  int* fill  = (int*)alloc((size_t)N*4);
  int* incl  = (int*)alloc((size_t)N*4);
  int* part  = (int*)alloc(256*4);
  int* csr   = (int*)alloc((size_t)E*4);
  float* mean = (float*)alloc((size_t)N*128*4);
  float* h_a  = (float*)alloc((size_t)N*128*4);
  float* h_b  = (float*)alloc((size_t)N*128*4);
  float* Wt[3];
  for (int i=0;i<3;i++) Wt[i] = (float*)alloc((size_t)258*dout[i]*4);

  hipMemsetAsync(deg, 0, (size_t)N*4, stream);
  hipMemsetAsync(fill, 0, (size_t)N*4, stream);

  int NB = CDIV(N,256);
  k_deg  <<<CDIV(E,256),256,0,stream>>>(edst, E, deg);
  k_scanA<<<NB,256,0,stream>>>(deg, N, incl, part);
  k_scanB<<<1,256,0,stream>>>(part, NB);
  k_scanC<<<NB,256,0,stream>>>(incl, part, N, off);
  k_fill <<<CDIV(E,256),256,0,stream>>>(esrc, edst, E, off, fill, csr);
  for (int i=0;i<3;i++)
    k_wt<<<CDIV(258*dout[i],256),256,0,stream>>>(Wl[i],bl[i],Wr[i],g[i],bb[i],rm[i],rv[i],dout[i],Wt[i]);

  const float* ins[3] = { x, h_a, h_b };
  float* outs[3] = { h_a, h_b, (float*)d_out };
  for (int i=0;i<3;i++){
    k_agg<<<CDIV(N*64,256),256,0,stream>>>(ins[i], off, csr, N, mean);
    if (dout[i] == 128){
      if (i < 2) k_gemm<128,true ><<<CDIV(N,64),256,0,stream>>>(mean, ins[i], Wt[i], outs[i], N);
      else       k_gemm<128,false><<<CDIV(N,64),256,0,stream>>>(mean, ins[i], Wt[i], outs[i], N);
    } else {
      if (i < 2) k_gemm<64,true ><<<CDIV(N,64),256,0,stream>>>(mean, ins[i], Wt[i], outs[i], N);
      else       k_gemm<64,false><<<CDIV(N,64),256,0,stream>>>(mean, ins[i], Wt[i], outs[i], N);
    }
  }
  k_norm<<<CDIV(N*64,256),256,0,stream>>>((float*)d_out, N);
}

// Round 2
// 349.617 us; speedup vs baseline: 1.5589x; 1.5589x over previous
//
#include <hip/hip_runtime.h>
#include <hip/hip_bf16.h>

#define CDIV(a,b) (((a)+(b)-1)/(b))

typedef __attribute__((ext_vector_type(8))) short short8;
typedef __attribute__((ext_vector_type(4))) float f32x4;

static __device__ __forceinline__ unsigned short f2bf(float f){
  union { float f; unsigned u; } v; v.f = f;
  unsigned r = v.u + 0x7fffu + ((v.u >> 16) & 1u);   // RNE
  return (unsigned short)(r >> 16);
}
static __device__ __forceinline__ float bfu_lo(unsigned u){
  union { unsigned u; float f; } v; v.u = u << 16; return v.f;
}
static __device__ __forceinline__ float bfu_hi(unsigned u){
  union { unsigned u; float f; } v; v.u = u & 0xffff0000u; return v.f;
}

// ---------------- CSR build ----------------

__global__ void k_deg(const int* __restrict__ dst, int E, int* __restrict__ deg){
  int i = blockIdx.x*256 + threadIdx.x;
  if (i < E) atomicAdd(&deg[dst[i]], 1);
}

__global__ void k_scanA(const int* __restrict__ deg, int n, int* __restrict__ incl, int* __restrict__ part){
  __shared__ int s[256];
  int t = threadIdx.x, i = blockIdx.x*256 + t;
  int v = (i<n) ? deg[i] : 0;
  s[t] = v; __syncthreads();
  for (int d=1; d<256; d<<=1){
    int u = (t>=d) ? s[t-d] : 0;
    __syncthreads();
    s[t] += u;
    __syncthreads();
  }
  if (i<n) incl[i] = s[t];
  if (t==255) part[blockIdx.x] = s[255];
}

__global__ void k_scanB(int* __restrict__ part, int nb){
  __shared__ int s[256];
  int t = threadIdx.x;
  int v = (t<nb) ? part[t] : 0;
  s[t] = v; __syncthreads();
  for (int d=1; d<256; d<<=1){
    int u = (t>=d) ? s[t-d] : 0;
    __syncthreads();
    s[t] += u;
    __syncthreads();
  }
  if (t<nb) part[t] = s[t] - v;  // exclusive
}

__global__ void k_scanC(const int* __restrict__ incl, const int* __restrict__ part, int n, int* __restrict__ off){
  int i = blockIdx.x*256 + threadIdx.x;
  if (i<n) off[i+1] = incl[i] + part[blockIdx.x];
  if (i==0) off[0] = 0;
}

__global__ void k_fill(const int* __restrict__ src, const int* __restrict__ dst, int E,
                       const int* __restrict__ off, int* __restrict__ fill, int* __restrict__ csr){
  int e = blockIdx.x*256 + threadIdx.x;
  if (e < E){
    int d = dst[e];
    int p = atomicAdd(&fill[d], 1);
    csr[off[d] + p] = src[e];
  }
}

// ---------------- cast x (f32) -> bf16 packed ----------------

__global__ void k_cast(const float* __restrict__ x, int n2, unsigned* __restrict__ xb){
  int i = blockIdx.x*256 + threadIdx.x;
  if (i < n2){
    float2 v = ((const float2*)x)[i];
    xb[i] = (unsigned)f2bf(v.x) | ((unsigned)f2bf(v.y) << 16);
  }
}

// ---------------- weight pack: B-fragment order bf16 + BN scale/shift fp32 ----------------
// Bpk element idx: j = idx&7 (k within frag), lane = (idx>>3)&63, rest = idx>>9; nt = rest%NT, kk = rest/NT
// B[k][n] with n = nt*16 + (lane&15), k = kk*32 + (lane>>4)*8 + j; B[k][n] = k<128 ? Wl[n][k] : Wr[n][k-128]

__global__ void k_wtp(const float* __restrict__ Wl, const float* __restrict__ bl, const float* __restrict__ Wr,
                      const float* __restrict__ g, const float* __restrict__ b,
                      const float* __restrict__ rm, const float* __restrict__ rv,
                      int dout, unsigned short* __restrict__ Bpk,
                      float* __restrict__ sc, float* __restrict__ sh){
  int idx = blockIdx.x*256 + threadIdx.x;
  int NB16 = 256*dout;
  if (idx < NB16){
    int j = idx & 7, lane = (idx >> 3) & 63, rest = idx >> 9;
    int NT = dout >> 4;
    int nt = rest % NT, kk = rest / NT;
    int nn = nt*16 + (lane & 15);
    int k  = kk*32 + ((lane >> 4) * 8) + j;
    float v = (k < 128) ? Wl[nn*128 + k] : Wr[nn*128 + (k - 128)];
    Bpk[idx] = f2bf(v);
  } else if (idx < NB16 + dout){
    int jj = idx - NB16;
    float s = g[jj] * rsqrtf(rv[jj] + 1e-5f);
    sc[jj] = s;
    sh[jj] = (bl[jj] - rm[jj]) * s + b[jj];
  }
}

// ---------------- mean aggregation: one wave per node, CSR gather (bf16 rows) ----------------

__global__ void k_agg(const unsigned* __restrict__ hin, const int* __restrict__ off,
                      const int* __restrict__ csr, int n, unsigned* __restrict__ mean){
  int w = (blockIdx.x*256 + threadIdx.x) >> 6;
  int lane = threadIdx.x & 63;
  if (w >= n) return;
  int s0 = off[w], s1 = off[w+1];
  float ax = 0.f, ay = 0.f;
  int e = s0;
  for (; e + 4 <= s1; e += 4){
    int i0 = csr[e], i1 = csr[e+1], i2 = csr[e+2], i3 = csr[e+3];
    unsigned v0 = hin[(size_t)i0*64 + lane];
    unsigned v1 = hin[(size_t)i1*64 + lane];
    unsigned v2 = hin[(size_t)i2*64 + lane];
    unsigned v3 = hin[(size_t)i3*64 + lane];
    ax += (bfu_lo(v0) + bfu_lo(v1)) + (bfu_lo(v2) + bfu_lo(v3));
    ay += (bfu_hi(v0) + bfu_hi(v1)) + (bfu_hi(v2) + bfu_hi(v3));
  }
  for (; e < s1; e++){
    unsigned v = hin[(size_t)csr[e]*64 + lane];
    ax += bfu_lo(v); ay += bfu_hi(v);
  }
  int d = s1 - s0;
  float inv = 1.0f / (float)(d > 0 ? d : 1);
  mean[(size_t)w*64 + lane] = (unsigned)f2bf(ax*inv) | ((unsigned)f2bf(ay*inv) << 16);
}

// ---------------- bf16 MFMA dual-GEMM + BN (+ReLU | +L2-norm) ----------------
// C[N][DOUT] = [mean | x] @ B, A rows bf16 N x 128 each (K=256 total).
// Block: 256 thr = 4 waves; wave covers 32 rows (2 M-tiles), all DOUT cols.
// B staged once in LDS (frag-packed) -> no barriers in K-loop.

template<int DOUT, bool FINAL>
__global__ __launch_bounds__(256, 2) void k_gemm_mfma(
    const unsigned short* __restrict__ Am, const unsigned short* __restrict__ Ax,
    const unsigned short* __restrict__ Bpk, const float* __restrict__ sc,
    const float* __restrict__ sh, float* __restrict__ outf,
    unsigned short* __restrict__ outb, int n){
  constexpr int NT = DOUT/16;
  __shared__ unsigned short Bs[256*DOUT];
  int t = threadIdx.x;
  {
    const uint4* s = (const uint4*)Bpk;
    uint4* d = (uint4*)Bs;
    constexpr int NV = 256*DOUT/8;
    #pragma unroll
    for (int i=0;i<NV/256;i++) d[i*256 + t] = s[i*256 + t];
  }
  __syncthreads();

  int lane = t & 63, w = t >> 6;
  int quad = lane >> 4, c = lane & 15;
  int m_base = blockIdx.x*128 + w*32;
  int r0 = m_base + c;
  int r1 = r0 + 16;

  f32x4 acc[2][NT];
  #pragma unroll
  for (int mt=0;mt<2;mt++)
    #pragma unroll
    for (int nt=0;nt<NT;nt++) acc[mt][nt] = (f32x4){0.f,0.f,0.f,0.f};

  #pragma unroll
  for (int kk=0; kk<8; kk++){
    const unsigned short* ab = (kk < 4) ? Am : Ax;
    int ka = (kk & 3)*32 + quad*8;
    short8 a0 = {0,0,0,0,0,0,0,0}, a1 = {0,0,0,0,0,0,0,0};
    if (r0 < n) a0 = *(const short8*)(ab + (size_t)r0*128 + ka);
    if (r1 < n) a1 = *(const short8*)(ab + (size_t)r1*128 + ka);
    #pragma unroll
    for (int nt=0; nt<NT; nt++){
      short8 b = *(const short8*)&Bs[(size_t)((kk*NT + nt)*64 + lane)*8];
      acc[0][nt] = __builtin_amdgcn_mfma_f32_16x16x32_bf16(a0, b, acc[0][nt], 0, 0, 0);
      acc[1][nt] = __builtin_amdgcn_mfma_f32_16x16x32_bf16(a1, b, acc[1][nt], 0, 0, 0);
    }
  }

  float scv[NT], shv[NT];
  #pragma unroll
  for (int nt=0;nt<NT;nt++){ scv[nt] = sc[nt*16 + c]; shv[nt] = sh[nt*16 + c]; }

  #pragma unroll
  for (int mt=0; mt<2; mt++){
    float v[NT][4];
    #pragma unroll
    for (int nt=0;nt<NT;nt++)
      #pragma unroll
      for (int r=0;r<4;r++){
        float u = acc[mt][nt][r]*scv[nt] + shv[nt];
        if (!FINAL) u = fmaxf(u, 0.f);
        v[nt][r] = u;
      }
    if constexpr (FINAL){
      // row L2-normalize: row = m_base + mt*16 + quad*4 + r; full row held by 16 lanes of this quad
      #pragma unroll
      for (int r=0;r<4;r++){
        float ss = 0.f;
        #pragma unroll
        for (int nt=0;nt<NT;nt++) ss += v[nt][r]*v[nt][r];
        ss += __shfl_xor(ss, 1, 64);
        ss += __shfl_xor(ss, 2, 64);
        ss += __shfl_xor(ss, 4, 64);
        ss += __shfl_xor(ss, 8, 64);
        float rn = 1.0f / fmaxf(sqrtf(ss), 1e-12f);
        int row = m_base + mt*16 + quad*4 + r;
        if (row < n){
          #pragma unroll
          for (int nt=0;nt<NT;nt++) outf[(size_t)row*DOUT + nt*16 + c] = v[nt][r]*rn;
        }
      }
    } else {
      #pragma unroll
      for (int r=0;r<4;r++){
        int row = m_base + mt*16 + quad*4 + r;
        if (row < n){
          #pragma unroll
          for (int nt=0;nt<NT;nt++) outb[(size_t)row*DOUT + nt*16 + c] = f2bf(v[nt][r]);
        }
      }
    }
  }
}

// ---------------- launcher ----------------

extern "C" void kernel_launch(void* const* d_in, const int* in_sizes, int n_in,
                              void* d_out, int out_size, void* d_ws, size_t ws_size,
                              hipStream_t stream){
  const float* x = (const float*)d_in[0];
  const int* ei  = (const int*)d_in[1];
  int N = in_sizes[0] / 128;
  int E = in_sizes[1] / 2;
  const int* esrc = ei;
  const int* edst = ei + E;

  const float *Wl[3], *bl[3], *Wr[3], *g[3], *bb[3], *rm[3], *rv[3];
  int dout[3];
  for (int i=0;i<3;i++){
    int base = 2 + 7*i;
    Wl[i]=(const float*)d_in[base];   bl[i]=(const float*)d_in[base+1];
    Wr[i]=(const float*)d_in[base+2]; g[i] =(const float*)d_in[base+3];
    bb[i]=(const float*)d_in[base+4]; rm[i]=(const float*)d_in[base+5];
    rv[i]=(const float*)d_in[base+6];
    dout[i] = in_sizes[base] / 128;
  }

  char* p = (char*)d_ws;
  size_t o = 0;
  auto alloc = [&](size_t bytes)->void*{ void* r = p + o; o += (bytes + 255) & ~(size_t)255; return r; };
  int* deg   = (int*)alloc((size_t)N*4);
  int* off   = (int*)alloc((size_t)(N+1)*4);
  int* fill  = (int*)alloc((size_t)N*4);
  int* incl  = (int*)alloc((size_t)N*4);
  int* part  = (int*)alloc(256*4);
  int* csr   = (int*)alloc((size_t)E*4);
  unsigned* xb   = (unsigned*)alloc((size_t)N*64*4);   // bf16 x, packed pairs
  unsigned* mb   = (unsigned*)alloc((size_t)N*64*4);   // bf16 mean
  unsigned* h_a  = (unsigned*)alloc((size_t)N*64*4);   // bf16 hidden 1
  unsigned* h_b  = (unsigned*)alloc((size_t)N*64*4);   // bf16 hidden 2
  unsigned short* Bpk[3]; float* sc[3]; float* sh[3];
  for (int i=0;i<3;i++){
    Bpk[i] = (unsigned short*)alloc((size_t)256*dout[i]*2);
    sc[i]  = (float*)alloc((size_t)dout[i]*4);
    sh[i]  = (float*)alloc((size_t)dout[i]*4);
  }

  hipMemsetAsync(deg, 0, (size_t)N*4, stream);
  hipMemsetAsync(fill, 0, (size_t)N*4, stream);

  int NB = CDIV(N,256);
  k_deg  <<<CDIV(E,256),256,0,stream>>>(edst, E, deg);
  k_scanA<<<NB,256,0,stream>>>(deg, N, incl, part);
  k_scanB<<<1,256,0,stream>>>(part, NB);
  k_scanC<<<NB,256,0,stream>>>(incl, part, N, off);
  k_fill <<<CDIV(E,256),256,0,stream>>>(esrc, edst, E, off, fill, csr);
  k_cast <<<CDIV(N*64,256),256,0,stream>>>(x, N*64, xb);
  for (int i=0;i<3;i++)
    k_wtp<<<CDIV(258*dout[i],256),256,0,stream>>>(Wl[i],bl[i],Wr[i],g[i],bb[i],rm[i],rv[i],
                                                  dout[i], Bpk[i], sc[i], sh[i]);

  const unsigned* ins[3] = { xb, h_a, h_b };
  unsigned* outs[3] = { h_a, h_b, nullptr };
  for (int i=0;i<3;i++){
    k_agg<<<CDIV(N*64,256),256,0,stream>>>(ins[i], off, csr, N, mb);
    const unsigned short* Amp = (const unsigned short*)mb;
    const unsigned short* Axp = (const unsigned short*)ins[i];
    if (i < 2){
      k_gemm_mfma<128,false><<<CDIV(N,128),256,0,stream>>>(Amp, Axp, Bpk[i], sc[i], sh[i],
                                                           nullptr, (unsigned short*)outs[i], N);
    } else {
      k_gemm_mfma<64,true><<<CDIV(N,128),256,0,stream>>>(Amp, Axp, Bpk[i], sc[i], sh[i],
                                                         (float*)d_out, nullptr, N);
    }
  }
}

// Round 3
// 317.405 us; speedup vs baseline: 1.7171x; 1.1015x over previous
//
#include <hip/hip_runtime.h>
#include <hip/hip_bf16.h>

#define CDIV(a,b) (((a)+(b)-1)/(b))
#define NBUCK_MAX 512   // buckets of 128 nodes; supports N up to 65536

typedef __attribute__((ext_vector_type(8))) short short8;
typedef __attribute__((ext_vector_type(4))) float f32x4;

static __device__ __forceinline__ unsigned short f2bf(float f){
  union { float f; unsigned u; } v; v.f = f;
  unsigned r = v.u + 0x7fffu + ((v.u >> 16) & 1u);   // RNE
  return (unsigned short)(r >> 16);
}
static __device__ __forceinline__ unsigned pack2(float lo, float hi){
  return (unsigned)f2bf(lo) | ((unsigned)f2bf(hi) << 16);
}
static __device__ __forceinline__ float bfu_lo(unsigned u){
  union { unsigned u; float f; } v; v.u = u << 16; return v.f;
}
static __device__ __forceinline__ float bfu_hi(unsigned u){
  union { unsigned u; float f; } v; v.u = u & 0xffff0000u; return v.f;
}

// ---------------- CSR build ----------------

__global__ void k_deg(const int* __restrict__ dst, int E, int* __restrict__ deg){
  int i = blockIdx.x*256 + threadIdx.x;
  if (i < E) atomicAdd(&deg[dst[i]], 1);
}

__global__ void k_scanA(const int* __restrict__ deg, int n, int* __restrict__ incl, int* __restrict__ part){
  __shared__ int s[256];
  int t = threadIdx.x, i = blockIdx.x*256 + t;
  int v = (i<n) ? deg[i] : 0;
  s[t] = v; __syncthreads();
  for (int d=1; d<256; d<<=1){
    int u = (t>=d) ? s[t-d] : 0;
    __syncthreads();
    s[t] += u;
    __syncthreads();
  }
  if (i<n) incl[i] = s[t];
  if (t==255) part[blockIdx.x] = s[255];
}

__global__ void k_scanB(int* __restrict__ part, int nb){
  __shared__ int s[256];
  int t = threadIdx.x;
  int v = (t<nb) ? part[t] : 0;
  s[t] = v; __syncthreads();
  for (int d=1; d<256; d<<=1){
    int u = (t>=d) ? s[t-d] : 0;
    __syncthreads();
    s[t] += u;
    __syncthreads();
  }
  if (t<nb) part[t] = s[t] - v;  // exclusive
}

__global__ void k_scanC(const int* __restrict__ incl, const int* __restrict__ part, int n, int* __restrict__ off){
  int i = blockIdx.x*256 + threadIdx.x;
  if (i<n) off[i+1] = incl[i] + part[blockIdx.x];
  if (i==0) off[0] = 0;
}

// Pass A: bin edges into 128-node buckets; bucket region in ebuf == final csr region.
__global__ __launch_bounds__(256) void k_bucketA(const int* __restrict__ src, const int* __restrict__ dst,
                                                 int E, const int* __restrict__ off,
                                                 int* __restrict__ bcur, uint2* __restrict__ ebuf, int nbuck){
  __shared__ int scnt[NBUCK_MAX];
  __shared__ int sbase[NBUCK_MAX];
  __shared__ int sboff[NBUCK_MAX];
  int t = threadIdx.x;
  for (int i=t;i<nbuck;i+=256) scnt[i] = 0;
  __syncthreads();
  constexpr int EPT = 16;
  int e0 = blockIdx.x*256*EPT;
  int b[EPT], s[EPT], d[EPT];
  #pragma unroll
  for (int i=0;i<EPT;i++){
    int e = e0 + i*256 + t;
    if (e < E){
      d[i] = dst[e]; s[i] = src[e]; b[i] = d[i] >> 7;
      atomicAdd(&scnt[b[i]], 1);
    } else b[i] = -1;
  }
  __syncthreads();
  for (int i=t;i<nbuck;i+=256){
    int c = scnt[i];
    sbase[i] = (c > 0) ? atomicAdd(&bcur[i], c) : 0;
    sboff[i] = off[i << 7];
    scnt[i] = 0;
  }
  __syncthreads();
  #pragma unroll
  for (int i=0;i<EPT;i++){
    if (b[i] >= 0){
      int p = atomicAdd(&scnt[b[i]], 1);
      ebuf[(size_t)sboff[b[i]] + sbase[b[i]] + p] = make_uint2((unsigned)s[i], (unsigned)d[i]);
    }
  }
}

// Pass B: one block per bucket; LDS cursors; csr writes confined to ~8KB window.
__global__ __launch_bounds__(256) void k_bucketB(const uint2* __restrict__ ebuf, const int* __restrict__ off,
                                                 int N, int* __restrict__ csr){
  int b = blockIdx.x;
  int n0 = b << 7, n1 = min(n0 + 128, N);
  __shared__ int loff[129];
  __shared__ int cur[128];
  int t = threadIdx.x;
  if (t <= n1 - n0) loff[t] = off[n0 + t];
  if (t < 128) cur[t] = 0;
  __syncthreads();
  int e1 = loff[n1 - n0];
  for (int e = loff[0] + t; e < e1; e += 256){
    uint2 pr = ebuf[e];
    int ln = (int)pr.y - n0;
    int p = atomicAdd(&cur[ln], 1);
    csr[loff[ln] + p] = (int)pr.x;
  }
}

// ---------------- cast x (f32) -> bf16 packed ----------------

__global__ void k_cast(const float* __restrict__ x, int n2, unsigned* __restrict__ xb){
  int i = blockIdx.x*256 + threadIdx.x;
  if (i < n2){
    float2 v = ((const float2*)x)[i];
    xb[i] = pack2(v.x, v.y);
  }
}

// ---------------- weight pack: B-fragment order bf16 + BN scale/shift fp32 ----------------

__global__ void k_wtp(const float* __restrict__ Wl, const float* __restrict__ bl, const float* __restrict__ Wr,
                      const float* __restrict__ g, const float* __restrict__ b,
                      const float* __restrict__ rm, const float* __restrict__ rv,
                      int dout, unsigned short* __restrict__ Bpk,
                      float* __restrict__ sc, float* __restrict__ sh){
  int idx = blockIdx.x*256 + threadIdx.x;
  int NB16 = 256*dout;
  if (idx < NB16){
    int j = idx & 7, lane = (idx >> 3) & 63, rest = idx >> 9;
    int NT = dout >> 4;
    int nt = rest % NT, kk = rest / NT;
    int nn = nt*16 + (lane & 15);
    int k  = kk*32 + ((lane >> 4) * 8) + j;
    float v = (k < 128) ? Wl[nn*128 + k] : Wr[nn*128 + (k - 128)];
    Bpk[idx] = f2bf(v);
  } else if (idx < NB16 + dout){
    int jj = idx - NB16;
    float s = g[jj] * rsqrtf(rv[jj] + 1e-5f);
    sc[jj] = s;
    sh[jj] = (bl[jj] - rm[jj]) * s + b[jj];
  }
}

// ---------------- mean aggregation: 4 nodes per wave, 16 lanes x uint4 per row ----------------

__global__ __launch_bounds__(256) void k_agg(const uint4* __restrict__ hin4, const int* __restrict__ off,
                                             const int* __restrict__ csr, int n, uint4* __restrict__ mean4){
  int tid = blockIdx.x*256 + threadIdx.x;
  int lane = threadIdx.x & 63;
  int sl = lane & 15, q = lane >> 4;
  int node = (tid >> 6)*4 + q;
  bool valid = node < n;
  int s0 = valid ? off[node]   : 0;
  int s1 = valid ? off[node+1] : 0;
  float a0=0,a1=0,a2=0,a3=0,a4=0,a5=0,a6=0,a7=0;
  int e = s0;
  for (; e + 2 <= s1; e += 2){
    int i0 = csr[e], i1 = csr[e+1];
    uint4 v0 = hin4[(size_t)i0*16 + sl];
    uint4 v1 = hin4[(size_t)i1*16 + sl];
    a0 += bfu_lo(v0.x) + bfu_lo(v1.x);  a1 += bfu_hi(v0.x) + bfu_hi(v1.x);
    a2 += bfu_lo(v0.y) + bfu_lo(v1.y);  a3 += bfu_hi(v0.y) + bfu_hi(v1.y);
    a4 += bfu_lo(v0.z) + bfu_lo(v1.z);  a5 += bfu_hi(v0.z) + bfu_hi(v1.z);
    a6 += bfu_lo(v0.w) + bfu_lo(v1.w);  a7 += bfu_hi(v0.w) + bfu_hi(v1.w);
  }
  if (e < s1){
    uint4 v = hin4[(size_t)csr[e]*16 + sl];
    a0 += bfu_lo(v.x); a1 += bfu_hi(v.x); a2 += bfu_lo(v.y); a3 += bfu_hi(v.y);
    a4 += bfu_lo(v.z); a5 += bfu_hi(v.z); a6 += bfu_lo(v.w); a7 += bfu_hi(v.w);
  }
  if (valid){
    int d = s1 - s0;
    float inv = 1.0f / (float)(d > 0 ? d : 1);
    uint4 o;
    o.x = pack2(a0*inv, a1*inv);
    o.y = pack2(a2*inv, a3*inv);
    o.z = pack2(a4*inv, a5*inv);
    o.w = pack2(a6*inv, a7*inv);
    mean4[(size_t)node*16 + sl] = o;
  }
}

// ---------------- bf16 MFMA dual-GEMM + BN (+ReLU | +L2-norm) ----------------

template<int DOUT, bool FINAL>
__global__ __launch_bounds__(256, 2) void k_gemm_mfma(
    const unsigned short* __restrict__ Am, const unsigned short* __restrict__ Ax,
    const unsigned short* __restrict__ Bpk, const float* __restrict__ sc,
    const float* __restrict__ sh, float* __restrict__ outf,
    unsigned short* __restrict__ outb, int n){
  constexpr int NT = DOUT/16;
  __shared__ unsigned short Bs[256*DOUT];
  int t = threadIdx.x;
  {
    const uint4* s = (const uint4*)Bpk;
    uint4* d = (uint4*)Bs;
    constexpr int NV = 256*DOUT/8;
    #pragma unroll
    for (int i=0;i<NV/256;i++) d[i*256 + t] = s[i*256 + t];
  }
  __syncthreads();

  int lane = t & 63, w = t >> 6;
  int quad = lane >> 4, c = lane & 15;
  int m_base = blockIdx.x*128 + w*32;
  int r0 = m_base + c;
  int r1 = r0 + 16;

  f32x4 acc[2][NT];
  #pragma unroll
  for (int mt=0;mt<2;mt++)
    #pragma unroll
    for (int nt=0;nt<NT;nt++) acc[mt][nt] = (f32x4){0.f,0.f,0.f,0.f};

  #pragma unroll
  for (int kk=0; kk<8; kk++){
    const unsigned short* ab = (kk < 4) ? Am : Ax;
    int ka = (kk & 3)*32 + quad*8;
    short8 a0 = {0,0,0,0,0,0,0,0}, a1 = {0,0,0,0,0,0,0,0};
    if (r0 < n) a0 = *(const short8*)(ab + (size_t)r0*128 + ka);
    if (r1 < n) a1 = *(const short8*)(ab + (size_t)r1*128 + ka);
    #pragma unroll
    for (int nt=0; nt<NT; nt++){
      short8 b = *(const short8*)&Bs[(size_t)((kk*NT + nt)*64 + lane)*8];
      acc[0][nt] = __builtin_amdgcn_mfma_f32_16x16x32_bf16(a0, b, acc[0][nt], 0, 0, 0);
      acc[1][nt] = __builtin_amdgcn_mfma_f32_16x16x32_bf16(a1, b, acc[1][nt], 0, 0, 0);
    }
  }

  float scv[NT], shv[NT];
  #pragma unroll
  for (int nt=0;nt<NT;nt++){ scv[nt] = sc[nt*16 + c]; shv[nt] = sh[nt*16 + c]; }

  #pragma unroll
  for (int mt=0; mt<2; mt++){
    float v[NT][4];
    #pragma unroll
    for (int nt=0;nt<NT;nt++)
      #pragma unroll
      for (int r=0;r<4;r++){
        float u = acc[mt][nt][r]*scv[nt] + shv[nt];
        if (!FINAL) u = fmaxf(u, 0.f);
        v[nt][r] = u;
      }
    if constexpr (FINAL){
      #pragma unroll
      for (int r=0;r<4;r++){
        float ss = 0.f;
        #pragma unroll
        for (int nt=0;nt<NT;nt++) ss += v[nt][r]*v[nt][r];
        ss += __shfl_xor(ss, 1, 64);
        ss += __shfl_xor(ss, 2, 64);
        ss += __shfl_xor(ss, 4, 64);
        ss += __shfl_xor(ss, 8, 64);
        float rn = 1.0f / fmaxf(sqrtf(ss), 1e-12f);
        int row = m_base + mt*16 + quad*4 + r;
        if (row < n){
          #pragma unroll
          for (int nt=0;nt<NT;nt++) outf[(size_t)row*DOUT + nt*16 + c] = v[nt][r]*rn;
        }
      }
    } else {
      #pragma unroll
      for (int r=0;r<4;r++){
        int row = m_base + mt*16 + quad*4 + r;
        if (row < n){
          #pragma unroll
          for (int nt=0;nt<NT;nt++) outb[(size_t)row*DOUT + nt*16 + c] = f2bf(v[nt][r]);
        }
      }
    }
  }
}

// ---------------- launcher ----------------

extern "C" void kernel_launch(void* const* d_in, const int* in_sizes, int n_in,
                              void* d_out, int out_size, void* d_ws, size_t ws_size,
                              hipStream_t stream){
  const float* x = (const float*)d_in[0];
  const int* ei  = (const int*)d_in[1];
  int N = in_sizes[0] / 128;
  int E = in_sizes[1] / 2;
  const int* esrc = ei;
  const int* edst = ei + E;
  int nbuck = CDIV(N, 128);

  const float *Wl[3], *bl[3], *Wr[3], *g[3], *bb[3], *rm[3], *rv[3];
  int dout[3];
  for (int i=0;i<3;i++){
    int base = 2 + 7*i;
    Wl[i]=(const float*)d_in[base];   bl[i]=(const float*)d_in[base+1];
    Wr[i]=(const float*)d_in[base+2]; g[i] =(const float*)d_in[base+3];
    bb[i]=(const float*)d_in[base+4]; rm[i]=(const float*)d_in[base+5];
    rv[i]=(const float*)d_in[base+6];
    dout[i] = in_sizes[base] / 128;
  }

  char* p = (char*)d_ws;
  size_t o = 0;
  auto alloc = [&](size_t bytes)->void*{ void* r = p + o; o += (bytes + 255) & ~(size_t)255; return r; };
  int* deg   = (int*)alloc((size_t)N*4);
  int* bcur  = (int*)alloc((size_t)nbuck*4);
  int* off   = (int*)alloc((size_t)(N+1)*4);
  int* incl  = (int*)alloc((size_t)N*4);
  int* part  = (int*)alloc(256*4);
  int* csr   = (int*)alloc((size_t)E*4);
  uint2* ebuf = (uint2*)alloc((size_t)E*8);
  unsigned* xb   = (unsigned*)alloc((size_t)N*64*4);
  unsigned* mb   = (unsigned*)alloc((size_t)N*64*4);
  unsigned* h_a  = (unsigned*)alloc((size_t)N*64*4);
  unsigned* h_b  = (unsigned*)alloc((size_t)N*64*4);
  unsigned short* Bpk[3]; float* sc[3]; float* sh[3];
  for (int i=0;i<3;i++){
    Bpk[i] = (unsigned short*)alloc((size_t)256*dout[i]*2);
    sc[i]  = (float*)alloc((size_t)dout[i]*4);
    sh[i]  = (float*)alloc((size_t)dout[i]*4);
  }

  hipMemsetAsync(deg, 0, (size_t)N*4, stream);
  hipMemsetAsync(bcur, 0, (size_t)nbuck*4, stream);

  int NB = CDIV(N,256);
  k_deg    <<<CDIV(E,256),256,0,stream>>>(edst, E, deg);
  k_scanA  <<<NB,256,0,stream>>>(deg, N, incl, part);
  k_scanB  <<<1,256,0,stream>>>(part, NB);
  k_scanC  <<<NB,256,0,stream>>>(incl, part, N, off);
  k_bucketA<<<CDIV(E,256*16),256,0,stream>>>(esrc, edst, E, off, bcur, ebuf, nbuck);
  k_bucketB<<<nbuck,256,0,stream>>>(ebuf, off, N, csr);
  k_cast   <<<CDIV(N*64,256),256,0,stream>>>(x, N*64, xb);
  for (int i=0;i<3;i++)
    k_wtp<<<CDIV(258*dout[i],256),256,0,stream>>>(Wl[i],bl[i],Wr[i],g[i],bb[i],rm[i],rv[i],
                                                  dout[i], Bpk[i], sc[i], sh[i]);

  const unsigned* ins[3] = { xb, h_a, h_b };
  unsigned* outs[3] = { h_a, h_b, nullptr };
  for (int i=0;i<3;i++){
    k_agg<<<CDIV(N*16,256),256,0,stream>>>((const uint4*)ins[i], off, csr, N, (uint4*)mb);
    const unsigned short* Amp = (const unsigned short*)mb;
    const unsigned short* Axp = (const unsigned short*)ins[i];
    if (i < 2){
      k_gemm_mfma<128,false><<<CDIV(N,128),256,0,stream>>>(Amp, Axp, Bpk[i], sc[i], sh[i],
                                                           nullptr, (unsigned short*)outs[i], N);
    } else {
      k_gemm_mfma<64,true><<<CDIV(N,128),256,0,stream>>>(Amp, Axp, Bpk[i], sc[i], sh[i],
                                                         (float*)d_out, nullptr, N);
    }
  }
}

// Round 4
// 271.888 us; speedup vs baseline: 2.0046x; 1.1674x over previous
//
#include <hip/hip_runtime.h>
#include <hip/hip_bf16.h>

#define CDIV(a,b) (((a)+(b)-1)/(b))
#define NBUCK_MAX 512   // buckets of 128 nodes; supports N up to 65536

typedef __attribute__((ext_vector_type(8))) short short8;
typedef __attribute__((ext_vector_type(4))) float f32x4;

static __device__ __forceinline__ unsigned short f2bf(float f){
  union { float f; unsigned u; } v; v.f = f;
  unsigned r = v.u + 0x7fffu + ((v.u >> 16) & 1u);   // RNE
  return (unsigned short)(r >> 16);
}
static __device__ __forceinline__ unsigned pack2(float lo, float hi){
  return (unsigned)f2bf(lo) | ((unsigned)f2bf(hi) << 16);
}
static __device__ __forceinline__ float bfu_lo(unsigned u){
  union { unsigned u; float f; } v; v.u = u << 16; return v.f;
}
static __device__ __forceinline__ float bfu_hi(unsigned u){
  union { unsigned u; float f; } v; v.u = u & 0xffff0000u; return v.f;
}
static __device__ __forceinline__ float bf2f(unsigned short s){
  union { unsigned u; float f; } v; v.u = ((unsigned)s) << 16; return v.f;
}

// ---------------- CSR build: bucket histogram -> scan -> bin -> local offsets ----------------

__global__ __launch_bounds__(256) void k_bhist(const int* __restrict__ dst, int E,
                                               int* __restrict__ bcnt, int nbuck){
  __shared__ int s[NBUCK_MAX];
  int t = threadIdx.x;
  for (int i=t;i<nbuck;i+=256) s[i] = 0;
  __syncthreads();
  constexpr int EPT = 16;
  int e0 = blockIdx.x*256*EPT;
  #pragma unroll
  for (int i=0;i<EPT;i++){
    int e = e0 + i*256 + t;
    if (e < E) atomicAdd(&s[dst[e] >> 7], 1);
  }
  __syncthreads();
  for (int i=t;i<nbuck;i+=256){
    int c = s[i];
    if (c > 0) atomicAdd(&bcnt[i], c);
  }
}

// single block: exclusive scan of bcnt[0..nbuck) -> bbase[0..nbuck], bbase[nbuck]=E
__global__ __launch_bounds__(256) void k_bscan(const int* __restrict__ bcnt, int nbuck,
                                               int* __restrict__ bbase){
  __shared__ int s[256];
  int t = threadIdx.x;
  int a0 = (2*t   < nbuck) ? bcnt[2*t]   : 0;
  int a1 = (2*t+1 < nbuck) ? bcnt[2*t+1] : 0;
  s[t] = a0 + a1; __syncthreads();
  for (int d=1; d<256; d<<=1){
    int u = (t>=d) ? s[t-d] : 0;
    __syncthreads();
    s[t] += u;
    __syncthreads();
  }
  int excl = s[t] - (a0 + a1);
  if (2*t   < nbuck) bbase[2*t]   = excl;
  if (2*t+1 < nbuck) bbase[2*t+1] = excl + a0;
  if (t == 255) bbase[nbuck] = s[255];
}

// Pass A: bin edges into 128-node buckets; bucket region in ebuf == final csr region.
__global__ __launch_bounds__(256) void k_bucketA(const int* __restrict__ src, const int* __restrict__ dst,
                                                 int E, const int* __restrict__ bbase,
                                                 int* __restrict__ bcur, uint2* __restrict__ ebuf, int nbuck){
  __shared__ int scnt[NBUCK_MAX];
  __shared__ int sbase[NBUCK_MAX];
  __shared__ int sboff[NBUCK_MAX];
  int t = threadIdx.x;
  for (int i=t;i<nbuck;i+=256) scnt[i] = 0;
  __syncthreads();
  constexpr int EPT = 16;
  int e0 = blockIdx.x*256*EPT;
  int b[EPT], s[EPT], d[EPT];
  #pragma unroll
  for (int i=0;i<EPT;i++){
    int e = e0 + i*256 + t;
    if (e < E){
      d[i] = dst[e]; s[i] = src[e]; b[i] = d[i] >> 7;
      atomicAdd(&scnt[b[i]], 1);
    } else b[i] = -1;
  }
  __syncthreads();
  for (int i=t;i<nbuck;i+=256){
    int c = scnt[i];
    sbase[i] = (c > 0) ? atomicAdd(&bcur[i], c) : 0;
    sboff[i] = bbase[i];
    scnt[i] = 0;
  }
  __syncthreads();
  #pragma unroll
  for (int i=0;i<EPT;i++){
    if (b[i] >= 0){
      int p = atomicAdd(&scnt[b[i]], 1);
      ebuf[(size_t)sboff[b[i]] + sbase[b[i]] + p] = make_uint2((unsigned)s[i], (unsigned)d[i]);
    }
  }
}

// Pass B: one block per bucket; local degree count + scan -> off + csr scatter in ~8KB window.
__global__ __launch_bounds__(256) void k_bucketB(const uint2* __restrict__ ebuf, const int* __restrict__ bbase,
                                                 int N, int* __restrict__ off, int* __restrict__ csr){
  int b = blockIdx.x;
  int n0 = b << 7, n1 = min(n0 + 128, N);
  __shared__ int sdeg[128];
  __shared__ int sabs[129];
  __shared__ int cur[128];
  int t = threadIdx.x;
  if (t < 128){ sdeg[t] = 0; cur[t] = 0; }
  __syncthreads();
  int e0 = bbase[b], e1 = bbase[b+1];
  for (int e = e0 + t; e < e1; e += 256)
    atomicAdd(&sdeg[(int)ebuf[e].y - n0], 1);
  __syncthreads();
  // inclusive scan of sdeg[0..128)
  for (int d=1; d<128; d<<=1){
    int u = (t < 128 && t >= d) ? sdeg[t-d] : 0;
    __syncthreads();
    if (t < 128) sdeg[t] += u;
    __syncthreads();
  }
  if (t == 0) sabs[0] = e0;
  if (t < 128) sabs[t+1] = e0 + sdeg[t];
  __syncthreads();
  if (t <= n1 - n0) off[n0 + t] = sabs[t];
  for (int e = e0 + t; e < e1; e += 256){
    uint2 pr = ebuf[e];
    int ln = (int)pr.y - n0;
    int p = atomicAdd(&cur[ln], 1);
    csr[sabs[ln] + p] = (int)pr.x;
  }
}

// ---------------- cast x (f32) -> bf16 packed ----------------

__global__ void k_cast(const float* __restrict__ x, int n2, unsigned* __restrict__ xb){
  int i = blockIdx.x*256 + threadIdx.x;
  if (i < n2){
    float2 v = ((const float2*)x)[i];
    xb[i] = pack2(v.x, v.y);
  }
}

// ---------------- weight pack: B-fragment order bf16 (+ optional BN scale/shift) ----------------
// Packs B[k][n], k in [0, kblk*32), n in [0,dout): k<128 -> W0[n][k], else W1[n][k-128]

__global__ void k_wtp(const float* __restrict__ W0, const float* __restrict__ W1,
                      const float* __restrict__ bl,
                      const float* __restrict__ g, const float* __restrict__ b,
                      const float* __restrict__ rm, const float* __restrict__ rv,
                      int kblk, int dout, unsigned short* __restrict__ Bpk,
                      float* __restrict__ sc, float* __restrict__ sh, int do_bn){
  int idx = blockIdx.x*256 + threadIdx.x;
  int NB16 = kblk*32*dout;
  if (idx < NB16){
    int j = idx & 7, lane = (idx >> 3) & 63, rest = idx >> 9;
    int NT = dout >> 4;
    int nt = rest % NT, kk = rest / NT;
    int nn = nt*16 + (lane & 15);
    int k  = kk*32 + ((lane >> 4) * 8) + j;
    float v = (k < 128) ? W0[nn*128 + k] : W1[nn*128 + (k - 128)];
    Bpk[idx] = f2bf(v);
  } else if (do_bn && idx < NB16 + dout){
    int jj = idx - NB16;
    float s = g[jj] * rsqrtf(rv[jj] + 1e-5f);
    sc[jj] = s;
    sh[jj] = (bl[jj] - rm[jj]) * s + b[jj];
  }
}

// ---------------- mean aggregation, 128-dim rows: 4 nodes/wave, 16 lanes x uint4 ----------------

__global__ __launch_bounds__(256) void k_agg(const uint4* __restrict__ hin4, const int* __restrict__ off,
                                             const int* __restrict__ csr, int n, uint4* __restrict__ mean4){
  int tid = blockIdx.x*256 + threadIdx.x;
  int lane = threadIdx.x & 63;
  int sl = lane & 15, q = lane >> 4;
  int node = (tid >> 6)*4 + q;
  bool valid = node < n;
  int s0 = valid ? off[node]   : 0;
  int s1 = valid ? off[node+1] : 0;
  float a0=0,a1=0,a2=0,a3=0,a4=0,a5=0,a6=0,a7=0;
  int e = s0;
  for (; e + 4 <= s1; e += 4){
    int i0 = csr[e], i1 = csr[e+1], i2 = csr[e+2], i3 = csr[e+3];
    uint4 v0 = hin4[(size_t)i0*16 + sl];
    uint4 v1 = hin4[(size_t)i1*16 + sl];
    uint4 v2 = hin4[(size_t)i2*16 + sl];
    uint4 v3 = hin4[(size_t)i3*16 + sl];
    a0 += (bfu_lo(v0.x)+bfu_lo(v1.x)) + (bfu_lo(v2.x)+bfu_lo(v3.x));
    a1 += (bfu_hi(v0.x)+bfu_hi(v1.x)) + (bfu_hi(v2.x)+bfu_hi(v3.x));
    a2 += (bfu_lo(v0.y)+bfu_lo(v1.y)) + (bfu_lo(v2.y)+bfu_lo(v3.y));
    a3 += (bfu_hi(v0.y)+bfu_hi(v1.y)) + (bfu_hi(v2.y)+bfu_hi(v3.y));
    a4 += (bfu_lo(v0.z)+bfu_lo(v1.z)) + (bfu_lo(v2.z)+bfu_lo(v3.z));
    a5 += (bfu_hi(v0.z)+bfu_hi(v1.z)) + (bfu_hi(v2.z)+bfu_hi(v3.z));
    a6 += (bfu_lo(v0.w)+bfu_lo(v1.w)) + (bfu_lo(v2.w)+bfu_lo(v3.w));
    a7 += (bfu_hi(v0.w)+bfu_hi(v1.w)) + (bfu_hi(v2.w)+bfu_hi(v3.w));
  }
  for (; e < s1; e++){
    uint4 v = hin4[(size_t)csr[e]*16 + sl];
    a0 += bfu_lo(v.x); a1 += bfu_hi(v.x); a2 += bfu_lo(v.y); a3 += bfu_hi(v.y);
    a4 += bfu_lo(v.z); a5 += bfu_hi(v.z); a6 += bfu_lo(v.w); a7 += bfu_hi(v.w);
  }
  if (valid){
    int d = s1 - s0;
    float inv = 1.0f / (float)(d > 0 ? d : 1);
    uint4 o;
    o.x = pack2(a0*inv, a1*inv);
    o.y = pack2(a2*inv, a3*inv);
    o.z = pack2(a4*inv, a5*inv);
    o.w = pack2(a6*inv, a7*inv);
    mean4[(size_t)node*16 + sl] = o;
  }
}

// ---------------- mean aggregation, 64-dim rows: 8 nodes/wave, 8 lanes x uint4 ----------------

__global__ __launch_bounds__(256) void k_agg64(const uint4* __restrict__ hin4, const int* __restrict__ off,
                                               const int* __restrict__ csr, int n, uint4* __restrict__ mean4){
  int tid = blockIdx.x*256 + threadIdx.x;
  int lane = threadIdx.x & 63;
  int sl = lane & 7, q = lane >> 3;
  int node = (tid >> 6)*8 + q;
  bool valid = node < n;
  int s0 = valid ? off[node]   : 0;
  int s1 = valid ? off[node+1] : 0;
  float a0=0,a1=0,a2=0,a3=0,a4=0,a5=0,a6=0,a7=0;
  int e = s0;
  for (; e + 4 <= s1; e += 4){
    int i0 = csr[e], i1 = csr[e+1], i2 = csr[e+2], i3 = csr[e+3];
    uint4 v0 = hin4[(size_t)i0*8 + sl];
    uint4 v1 = hin4[(size_t)i1*8 + sl];
    uint4 v2 = hin4[(size_t)i2*8 + sl];
    uint4 v3 = hin4[(size_t)i3*8 + sl];
    a0 += (bfu_lo(v0.x)+bfu_lo(v1.x)) + (bfu_lo(v2.x)+bfu_lo(v3.x));
    a1 += (bfu_hi(v0.x)+bfu_hi(v1.x)) + (bfu_hi(v2.x)+bfu_hi(v3.x));
    a2 += (bfu_lo(v0.y)+bfu_lo(v1.y)) + (bfu_lo(v2.y)+bfu_lo(v3.y));
    a3 += (bfu_hi(v0.y)+bfu_hi(v1.y)) + (bfu_hi(v2.y)+bfu_hi(v3.y));
    a4 += (bfu_lo(v0.z)+bfu_lo(v1.z)) + (bfu_lo(v2.z)+bfu_lo(v3.z));
    a5 += (bfu_hi(v0.z)+bfu_hi(v1.z)) + (bfu_hi(v2.z)+bfu_hi(v3.z));
    a6 += (bfu_lo(v0.w)+bfu_lo(v1.w)) + (bfu_lo(v2.w)+bfu_lo(v3.w));
    a7 += (bfu_hi(v0.w)+bfu_hi(v1.w)) + (bfu_hi(v2.w)+bfu_hi(v3.w));
  }
  for (; e < s1; e++){
    uint4 v = hin4[(size_t)csr[e]*8 + sl];
    a0 += bfu_lo(v.x); a1 += bfu_hi(v.x); a2 += bfu_lo(v.y); a3 += bfu_hi(v.y);
    a4 += bfu_lo(v.z); a5 += bfu_hi(v.z); a6 += bfu_lo(v.w); a7 += bfu_hi(v.w);
  }
  if (valid){
    int d = s1 - s0;
    float inv = 1.0f / (float)(d > 0 ? d : 1);
    uint4 o;
    o.x = pack2(a0*inv, a1*inv);
    o.y = pack2(a2*inv, a3*inv);
    o.z = pack2(a4*inv, a5*inv);
    o.w = pack2(a6*inv, a7*inv);
    mean4[(size_t)node*8 + sl] = o;
  }
}

// ---------------- bf16 MFMA GEMM, 3 modes ----------------
// MODE 0: hidden  — C = [A0|A1]@B (KBLK=8), BN+ReLU, bf16 out
// MODE 1: final   — C = A0@B (KBLK=4), += addb, BN, row-L2-normalize, f32 out
// MODE 2: linear  — C = A0@B (KBLK=4), bf16 out (no BN/ReLU)

template<int DOUT, int KBLK, int MODE>
__global__ __launch_bounds__(256, 2) void k_gemm_mfma(
    const unsigned short* __restrict__ A0, const unsigned short* __restrict__ A1,
    const unsigned short* __restrict__ Bpk, const float* __restrict__ sc,
    const float* __restrict__ sh, const unsigned short* __restrict__ addb,
    float* __restrict__ outf, unsigned short* __restrict__ outb, int n){
  constexpr int NT = DOUT/16;
  __shared__ unsigned short Bs[KBLK*32*DOUT];
  int t = threadIdx.x;
  {
    const uint4* s = (const uint4*)Bpk;
    uint4* d = (uint4*)Bs;
    constexpr int NV = KBLK*32*DOUT/8;
    #pragma unroll
    for (int i=0;i<NV/256;i++) d[i*256 + t] = s[i*256 + t];
  }
  __syncthreads();

  int lane = t & 63, w = t >> 6;
  int quad = lane >> 4, c = lane & 15;
  int m_base = blockIdx.x*128 + w*32;
  int r0 = m_base + c;
  int r1 = r0 + 16;

  f32x4 acc[2][NT];
  #pragma unroll
  for (int mt=0;mt<2;mt++)
    #pragma unroll
    for (int nt=0;nt<NT;nt++) acc[mt][nt] = (f32x4){0.f,0.f,0.f,0.f};

  #pragma unroll
  for (int kk=0; kk<KBLK; kk++){
    const unsigned short* ab = (KBLK == 8 && kk >= 4) ? A1 : A0;
    int ka = (kk & 3)*32 + quad*8;
    short8 a0 = {0,0,0,0,0,0,0,0}, a1 = {0,0,0,0,0,0,0,0};
    if (r0 < n) a0 = *(const short8*)(ab + (size_t)r0*128 + ka);
    if (r1 < n) a1 = *(const short8*)(ab + (size_t)r1*128 + ka);
    #pragma unroll
    for (int nt=0; nt<NT; nt++){
      short8 b = *(const short8*)&Bs[(size_t)((kk*NT + nt)*64 + lane)*8];
      acc[0][nt] = __builtin_amdgcn_mfma_f32_16x16x32_bf16(a0, b, acc[0][nt], 0, 0, 0);
      acc[1][nt] = __builtin_amdgcn_mfma_f32_16x16x32_bf16(a1, b, acc[1][nt], 0, 0, 0);
    }
  }

  float scv[NT], shv[NT];
  if constexpr (MODE != 2){
    #pragma unroll
    for (int nt=0;nt<NT;nt++){ scv[nt] = sc[nt*16 + c]; shv[nt] = sh[nt*16 + c]; }
  }

  #pragma unroll
  for (int mt=0; mt<2; mt++){
    #pragma unroll
    for (int r=0;r<4;r++){
      int row = m_base + mt*16 + quad*4 + r;
      if constexpr (MODE == 1){
        float v[NT];
        float ss = 0.f;
        if (row < n){
          #pragma unroll
          for (int nt=0;nt<NT;nt++){
            float u = acc[mt][nt][r] + bf2f(addb[(size_t)row*DOUT + nt*16 + c]);
            u = u*scv[nt] + shv[nt];
            v[nt] = u;
            ss += u*u;
          }
        } else {
          #pragma unroll
          for (int nt=0;nt<NT;nt++) v[nt] = 0.f;
        }
        ss += __shfl_xor(ss, 1, 64);
        ss += __shfl_xor(ss, 2, 64);
        ss += __shfl_xor(ss, 4, 64);
        ss += __shfl_xor(ss, 8, 64);
        float rn = 1.0f / fmaxf(sqrtf(ss), 1e-12f);
        if (row < n){
          #pragma unroll
          for (int nt=0;nt<NT;nt++) outf[(size_t)row*DOUT + nt*16 + c] = v[nt]*rn;
        }
      } else {
        if (row < n){
          #pragma unroll
          for (int nt=0;nt<NT;nt++){
            float u = acc[mt][nt][r];
            if constexpr (MODE == 0){
              u = u*scv[nt] + shv[nt];
              u = fmaxf(u, 0.f);
            }
            outb[(size_t)row*DOUT + nt*16 + c] = f2bf(u);
          }
        }
      }
    }
  }
}

// ---------------- launcher ----------------

extern "C" void kernel_launch(void* const* d_in, const int* in_sizes, int n_in,
                              void* d_out, int out_size, void* d_ws, size_t ws_size,
                              hipStream_t stream){
  const float* x = (const float*)d_in[0];
  const int* ei  = (const int*)d_in[1];
  int N = in_sizes[0] / 128;
  int E = in_sizes[1] / 2;
  const int* esrc = ei;
  const int* edst = ei + E;
  int nbuck = CDIV(N, 128);

  const float *Wl[3], *bl[3], *Wr[3], *g[3], *bb[3], *rm[3], *rv[3];
  int dout[3];
  for (int i=0;i<3;i++){
    int base = 2 + 7*i;
    Wl[i]=(const float*)d_in[base];   bl[i]=(const float*)d_in[base+1];
    Wr[i]=(const float*)d_in[base+2]; g[i] =(const float*)d_in[base+3];
    bb[i]=(const float*)d_in[base+4]; rm[i]=(const float*)d_in[base+5];
    rv[i]=(const float*)d_in[base+6];
    dout[i] = in_sizes[base] / 128;
  }

  char* p = (char*)d_ws;
  size_t o = 0;
  auto alloc = [&](size_t bytes)->void*{ void* r = p + o; o += (bytes + 255) & ~(size_t)255; return r; };
  int* bcnt  = (int*)alloc((size_t)nbuck*4);
  int* bbase = (int*)alloc((size_t)(nbuck+1)*4);
  int* bcur  = (int*)alloc((size_t)nbuck*4);
  int* off   = (int*)alloc((size_t)(N+1)*4);
  int* csr   = (int*)alloc((size_t)E*4);
  uint2* ebuf = (uint2*)alloc((size_t)E*8);
  unsigned* xb   = (unsigned*)alloc((size_t)N*64*4);
  unsigned* mb   = (unsigned*)alloc((size_t)N*64*4);
  unsigned* h_a  = (unsigned*)alloc((size_t)N*64*4);
  unsigned* h_b  = (unsigned*)alloc((size_t)N*64*4);
  unsigned* ylb  = (unsigned*)alloc((size_t)N*32*4);   // layer-3 yl (N x 64 bf16)
  unsigned* myl  = (unsigned*)alloc((size_t)N*32*4);   // layer-3 mean(yl)
  unsigned short* Bpk01[2];
  float* sc[3]; float* sh[3];
  for (int i=0;i<2;i++) Bpk01[i] = (unsigned short*)alloc((size_t)256*dout[i]*2);
  unsigned short* BpkL = (unsigned short*)alloc((size_t)128*dout[2]*2);
  unsigned short* BpkR = (unsigned short*)alloc((size_t)128*dout[2]*2);
  for (int i=0;i<3;i++){
    sc[i] = (float*)alloc((size_t)dout[i]*4);
    sh[i] = (float*)alloc((size_t)dout[i]*4);
  }

  hipMemsetAsync(bcnt, 0, (size_t)nbuck*4, stream);
  hipMemsetAsync(bcur, 0, (size_t)nbuck*4, stream);

  k_bhist  <<<CDIV(E,256*16),256,0,stream>>>(edst, E, bcnt, nbuck);
  k_bscan  <<<1,256,0,stream>>>(bcnt, nbuck, bbase);
  k_bucketA<<<CDIV(E,256*16),256,0,stream>>>(esrc, edst, E, bbase, bcur, ebuf, nbuck);
  k_bucketB<<<nbuck,256,0,stream>>>(ebuf, bbase, N, off, csr);
  k_cast   <<<CDIV(N*64,256),256,0,stream>>>(x, N*64, xb);
  for (int i=0;i<2;i++)
    k_wtp<<<CDIV(256*dout[i]+dout[i],256),256,0,stream>>>(Wl[i], Wr[i], bl[i], g[i], bb[i], rm[i], rv[i],
                                                          8, dout[i], Bpk01[i], sc[i], sh[i], 1);
  k_wtp<<<CDIV(128*dout[2],256),256,0,stream>>>(Wl[2], nullptr, nullptr, nullptr, nullptr, nullptr, nullptr,
                                                4, dout[2], BpkL, nullptr, nullptr, 0);
  k_wtp<<<CDIV(128*dout[2]+dout[2],256),256,0,stream>>>(Wr[2], nullptr, bl[2], g[2], bb[2], rm[2], rv[2],
                                                        4, dout[2], BpkR, sc[2], sh[2], 1);

  // layers 0,1: agg(128-dim) then dual-K GEMM
  const unsigned* ins[2] = { xb, h_a };
  unsigned* outs[2] = { h_a, h_b };
  for (int i=0;i<2;i++){
    k_agg<<<CDIV(N*16,256),256,0,stream>>>((const uint4*)ins[i], off, csr, N, (uint4*)mb);
    k_gemm_mfma<128,8,0><<<CDIV(N,128),256,0,stream>>>((const unsigned short*)mb, (const unsigned short*)ins[i],
                                                       Bpk01[i], sc[i], sh[i], nullptr,
                                                       nullptr, (unsigned short*)outs[i], N);
  }
  // layer 2: yl = h_b @ Wl^T; mean-agg yl (64-dim); final = BN(mean_yl + h_b@Wr^T) + L2norm
  k_gemm_mfma<64,4,2><<<CDIV(N,128),256,0,stream>>>((const unsigned short*)h_b, nullptr,
                                                    BpkL, nullptr, nullptr, nullptr,
                                                    nullptr, (unsigned short*)ylb, N);
  k_agg64<<<CDIV(N*8,256),256,0,stream>>>((const uint4*)ylb, off, csr, N, (uint4*)myl);
  k_gemm_mfma<64,4,1><<<CDIV(N,128),256,0,stream>>>((const unsigned short*)h_b, nullptr,
                                                    BpkR, sc[2], sh[2], (const unsigned short*)myl,
                                                    (float*)d_out, nullptr, N);
}